// Round 4
// baseline (228.780 us; speedup 1.0000x reference)
//
#include <hip/hip_runtime.h>
#include <hip/hip_bf16.h>
#include <cstdint>
#include <cstddef>

// Problem constants (fixed shapes per reference)
#define NROWS 8192
#define DIM   1024
#define BT    256          // square tile 256x256
#define BK    64           // K depth per staging step; 16 steps
#define NKT   (DIM / BK)
#define NFULL 496          // 31*32/2 strictly-lower full tiles (8 XCDs x 62)
#define NDD   16           // double-diagonal blocks (2 diag tiles each), FIRST
#define NBLK  (NFULL + NDD)     // 512 = exactly 2 rounds of 256 CUs
#define EPS 1e-8f
// E pre-scaled by sqrt(10*log2(e)) so MFMA accumulates 10*log2(e)*<a,b>;
// epilogue is a bare exp2f.
#define PRESCALE 3.798288f

// LDS: SINGLE buffer, A 256x64 + B 256x64 bf16 = 64 KB
#define ABUF_E 16384       // elems per A (or B) K-tile

typedef short  bf16x8  __attribute__((ext_vector_type(8)));
typedef float  floatx4 __attribute__((ext_vector_type(4)));

typedef __attribute__((address_space(1))) const void CGV;
typedef __attribute__((address_space(3))) void LV;

__device__ __forceinline__ void async_load16(const void* g, void* l) {
    __builtin_amdgcn_global_load_lds((CGV*)g, (LV*)l, 16, 0, 0);
}

__device__ __forceinline__ unsigned short f2bf_rne(float f) {
    union { float f; unsigned u; } c; c.f = f;
    unsigned u = c.u;
    unsigned r = (u + 0x7fffu + ((u >> 16) & 1u)) >> 16;
    return (unsigned short)r;
}

// ---------------------------------------------------------------------------
// Kernel A: fp32 -> bf16 (RNE) with PRESCALE folded in. First 64 blocks also
// zero the 16384-float accumulator region.
// ---------------------------------------------------------------------------
__global__ __launch_bounds__(256) void convert_kernel(
    const float* __restrict__ in, unsigned short* __restrict__ out,
    float* __restrict__ accum /* all_sum ++ pos_sum, 2*NROWS floats */)
{
    int i = (blockIdx.x * 256 + threadIdx.x) * 4;
    float4 v = *(const float4*)(in + i);
    ushort4 o;
    o.x = f2bf_rne(v.x * PRESCALE);
    o.y = f2bf_rne(v.y * PRESCALE);
    o.z = f2bf_rne(v.z * PRESCALE);
    o.w = f2bf_rne(v.w * PRESCALE);
    *(ushort4*)(out + i) = o;
    if (blockIdx.x < (2 * NROWS) / 256)
        accum[blockIdx.x * 256 + threadIdx.x] = 0.0f;
}

// ---------------------------------------------------------------------------
// run_tile<DIAG>: one 256x256 tile, m97/R0-shape loop — NO inline asm, NO
// sched_barrier, single LDS buffer, pure __syncthreads. R4 post-mortem of
// R2/R3: the asm "memory"-clobber waitcnts + sched_barrier(0) pinning
// collapsed sustained staging from ~10 TB/s (R0, asm-free) to 3.1 TB/s
// (m141 failure mode). This reverts to the PROVEN sync structure:
//   per K-step: sync; 8x global_load_lds; sync (compiler drains vmcnt);
//               24x ds_read_b128 + 64 MFMA (compiler fine-lgkmcnt).
// 256^2 tile halves staged volume vs R0's 128^2 (512 MB total vs 1065 MB).
// Swizzle (R3/R9/R11-verified, BK=64/128B rows): LDS slot s of row r holds
// global chunk s^(r&7); linear LDS dest (m104) + pre-swizzled global source
// (m173); read slot = ((ksub*4+quad) ^ (colw&7)). Verified 0 conflicts.
// DIAG: B panel == A panel -> skip B staging (half volume), read bF from the
// A region; liveMask skips all-strictly-upper 16x16 frags (epilogue
// grow>gcol rule zeroes them anyway); wn remap balances SIMD load (max
// 36/64 live frags per SIMD pair).
// ---------------------------------------------------------------------------
template<bool DIAG>
__device__ __forceinline__ void run_tile(
    const unsigned short* __restrict__ E,
    const int*            __restrict__ labels,
    float*                __restrict__ all_sum,
    float*                __restrict__ pos_sum,
    unsigned short* S, int rBase, int cBase)
{
    const int tid  = threadIdx.x;
    const int lane = tid & 63;
    const int w    = tid >> 6;      // wave 0..7
    const int wm   = w >> 2;        // row half (128 rows)
    // col quarter; w>=4 remapped [3,2,0,1] so SIMD pairs {w,w+4} balance
    // diag live-frag counts (36/36/32/32 of 64). Bijection — harmless for
    // full tiles.
    const int wn   = (w < 4) ? w : ((0x1023 >> ((w & 3) * 4)) & 0xF);
    const int colw = lane & 15;
    const int quad = lane >> 4;
    const int swz  = colw & 7;
    const int cs0  = ((0 | quad) ^ swz) << 3;   // ksub0 slot offset (elems)
    const int cs1  = ((4 | quad) ^ swz) << 3;   // ksub1

    // Stage addressing: thread covers row w*8+l8 of each 64-row block,
    // global chunk gch = (lane&7)^(l8&7) (pre-swizzled source; row&7
    // invariant under +8-row steps).
    const int l8  = lane >> 3;
    const int gch = (lane & 7) ^ l8;
    const unsigned short* gA = E + (size_t)(rBase + w * 8 + l8) * DIM + gch * 8;
    const unsigned short* gB = E + (size_t)(cBase + w * 8 + l8) * DIM + gch * 8;
    const int ldsT = w * 512 + lane * 8;   // lds elem offset within an 8KB block

    unsigned liveMask = 0xFFFFFFFFu;
    if (DIAG) {
        liveMask = 0u;
        #pragma unroll
        for (int mt = 0; mt < 8; ++mt)
            #pragma unroll
            for (int nt = 0; nt < 4; ++nt)
                if (wm * 128 + mt * 16 + 15 >= wn * 64 + nt * 16)
                    liveMask |= 1u << (mt * 4 + nt);
    }

    floatx4 acc[8][4];
    #pragma unroll
    for (int i = 0; i < 8; ++i)
        #pragma unroll
        for (int j = 0; j < 4; ++j)
            acc[i][j] = (floatx4)0.0f;

    const int bOff = DIAG ? 0 : ABUF_E;    // B frags read from A region if diag

    for (int kt = 0; kt < NKT; ++kt) {
        __syncthreads();   // previous compute done before overwrite

        // ---- stage K-tile kt (linear LDS dest; swizzled global source)
        const size_t gk = (size_t)kt * BK;
        #pragma unroll
        for (int rb = 0; rb < 256; rb += 64)
            async_load16(gA + (size_t)rb * DIM + gk, &S[rb * 64 + ldsT]);
        if (!DIAG) {
            #pragma unroll
            for (int rb = 0; rb < 256; rb += 64)
                async_load16(gB + (size_t)rb * DIM + gk,
                             &S[ABUF_E + rb * 64 + ldsT]);
        }

        __syncthreads();   // compiler drains vmcnt before barrier — tile ready

        // ---- compute: 2 ksubs x (8 aF + 4 bF ds_read_b128, 32 MFMA)
        #pragma unroll
        for (int ksub = 0; ksub < 2; ++ksub) {
            const int cs = ksub ? cs1 : cs0;
            bf16x8 bF[4], aF[8];
            #pragma unroll
            for (int nt = 0; nt < 4; ++nt)
                bF[nt] = *(const bf16x8*)&S[bOff +
                              (wn * 64 + nt * 16 + colw) * BK + cs];
            #pragma unroll
            for (int mt = 0; mt < 8; ++mt)
                aF[mt] = *(const bf16x8*)&S[
                              (wm * 128 + mt * 16 + colw) * BK + cs];
            #pragma unroll
            for (int mt = 0; mt < 8; ++mt) {
                #pragma unroll
                for (int nt = 0; nt < 4; ++nt) {
                    if (!DIAG || ((liveMask >> (mt * 4 + nt)) & 1u))
                        acc[mt][nt] = __builtin_amdgcn_mfma_f32_16x16x32_bf16(
                            aF[mt], bF[nt], acc[mt][nt], 0, 0, 0);
                }
            }
        }
    }

    // Epilogue. C/D layout (16x16x32): col = lane&15, row = quad*4 + reg.
    // Uniform rule: element (grow, gcol) counts iff grow > gcol; contributes
    // to row grow AND col gcol (R11-verified). Dead diag frags hold 0 and
    // are masked by the same rule.
    float labc[4];
    int   gcolv[4];
    #pragma unroll
    for (int nt = 0; nt < 4; ++nt) {
        gcolv[nt] = cBase + wn * 64 + nt * 16 + colw;
        labc[nt]  = (float)labels[gcolv[nt]];
    }

    float colAll[4] = {0.f, 0.f, 0.f, 0.f};
    float colPos[4] = {0.f, 0.f, 0.f, 0.f};

    #pragma unroll
    for (int mt = 0; mt < 8; ++mt) {
        const int growBase = rBase + wm * 128 + mt * 16 + quad * 4;
        #pragma unroll
        for (int r = 0; r < 4; ++r) {
            const int grow = growBase + r;
            const float labr = (float)labels[grow];
            float sAll = 0.f, sPos = 0.f;
            #pragma unroll
            for (int nt = 0; nt < 4; ++nt) {
                float ev = exp2f(acc[mt][nt][r]);   // PRESCALE folded into E
                ev = (grow > gcolv[nt]) ? ev : 0.0f; // strictly-lower only
                sAll += ev;
                sPos += ev * labc[nt];
                colAll[nt] += ev;
                colPos[nt] += ev * labr;
            }
            // row-reduce across the 16 lanes (same quad) sharing this row
            #pragma unroll
            for (int off = 1; off < 16; off <<= 1) {
                sAll += __shfl_xor(sAll, off);
                sPos += __shfl_xor(sPos, off);
            }
            if (colw == 0 && sAll != 0.f) {
                atomicAdd(&all_sum[grow], sAll);
                atomicAdd(&pos_sum[grow], sPos);
            }
        }
    }

    // col-reduce: sum across quads (lanes differing in bits 4,5)
    #pragma unroll
    for (int nt = 0; nt < 4; ++nt) {
        float aa = colAll[nt], p = colPos[nt];
        aa += __shfl_xor(aa, 16);  p += __shfl_xor(p, 16);
        aa += __shfl_xor(aa, 32);  p += __shfl_xor(p, 32);
        if (quad == 0 && aa != 0.f) {
            atomicAdd(&all_sum[gcolv[nt]], aa);
            atomicAdd(&pos_sum[gcolv[nt]], p);
        }
    }
}

// ---------------------------------------------------------------------------
// Kernel B driver: 512 blocks = 2 clean rounds of 256 CUs.
//   b <  16 : double-diagonal block (diag tiles 2b and 2b+1, sequential) —
//             dispatched FIRST so its ~2x(half-cost) runtime finishes at ~2T
//             alongside CUs running two full tiles (R3's dispatch-last
//             ordering pushed these into round 2 -> 3T makespan).
//   b >= 16 : strictly-lower full tile, XCD-chunked order for L2 locality.
// ---------------------------------------------------------------------------
__global__ __launch_bounds__(512, 2) void gemm_fused_kernel(
    const unsigned short* __restrict__ E,
    const int*            __restrict__ labels,
    float*                __restrict__ all_sum,
    float*                __restrict__ pos_sum)
{
    __shared__ __align__(16) unsigned short S[2 * ABUF_E];   // 64 KB

    const int b = blockIdx.x;
    if (b < NDD) {
        const int d0 = (2 * b) * BT;
        run_tile<true>(E, labels, all_sum, pos_sum, S, d0, d0);
        const int d1 = (2 * b + 1) * BT;
        run_tile<true>(E, labels, all_sum, pos_sum, S, d1, d1);
    } else {
        const int bp = b - NDD;
        const int t = (bp & 7) * 62 + (bp >> 3);    // 496 = 8 x 62, XCD-local
        int a = (int)((1.0f + sqrtf(1.0f + 8.0f * (float)t)) * 0.5f);
        while (a * (a - 1) / 2 > t) --a;
        while ((a + 1) * a / 2 <= t) ++a;
        const int c = t - a * (a - 1) / 2;          // c < a
        run_tile<false>(E, labels, all_sum, pos_sum, S, a * BT, c * BT);
    }
}

// ---------------------------------------------------------------------------
// Kernel C: loss = mean over rows with lab==1 of -log(pos/(all+eps)); 0 if n_ref<2
// ---------------------------------------------------------------------------
__global__ __launch_bounds__(1024) void finalize_kernel(
    const float* __restrict__ all_sum,
    const float* __restrict__ pos_sum,
    const int*   __restrict__ labels,
    float*       __restrict__ out)
{
    __shared__ float sSum[1024];
    __shared__ float sCnt[1024];
    const int tid = threadIdx.x;
    float lsum = 0.f, lcnt = 0.f;
    for (int i = tid; i < NROWS; i += 1024) {
        if (labels[i] > 0) {
            float p = pos_sum[i];
            float a = all_sum[i] + EPS;
            lsum += -logf(p / a);
            lcnt += 1.0f;
        }
    }
    sSum[tid] = lsum;
    sCnt[tid] = lcnt;
    __syncthreads();
    for (int s = 512; s > 0; s >>= 1) {
        if (tid < s) { sSum[tid] += sSum[tid + s]; sCnt[tid] += sCnt[tid + s]; }
        __syncthreads();
    }
    if (tid == 0) {
        float n = sCnt[0];
        out[0] = (n < 2.0f) ? 0.0f : sSum[0] / fmaxf(n, 1.0f);
    }
}

// ---------------------------------------------------------------------------
extern "C" void kernel_launch(void* const* d_in, const int* in_sizes, int n_in,
                              void* d_out, int out_size, void* d_ws, size_t ws_size,
                              hipStream_t stream) {
    const float* emb    = (const float*)d_in[0];
    const int*   labels = (const int*)d_in[1];
    float*       out    = (float*)d_out;

    // workspace layout: [bf16 E: 16 MB][all_sum: 32 KB][pos_sum: 32 KB]
    unsigned short* Ebf = (unsigned short*)d_ws;
    const size_t embBytes = (size_t)NROWS * DIM * sizeof(unsigned short);
    float* all_sum = (float*)((char*)d_ws + embBytes);
    float* pos_sum = all_sum + NROWS;

    convert_kernel<<<(NROWS * DIM) / (4 * 256), 256, 0, stream>>>(emb, Ebf, all_sum);

    gemm_fused_kernel<<<NBLK, 512, 0, stream>>>(Ebf, labels, all_sum, pos_sum);

    finalize_kernel<<<1, 1024, 0, stream>>>(all_sum, pos_sum, labels, out);
}